// Round 3
// baseline (29.417 us; speedup 1.0000x reference)
//
#include <hip/hip_runtime.h>

// PatchBlender, half-column-per-thread:
// Each thread owns one (b, p, e4) column for 8 consecutive output frames,
// loading the 9 input frames that contribute (1 halo). Doubles parallelism vs
// full-column threads (occupancy was 28%) while keeping reads ~1x (6% halo,
// absorbed by L3). Weights come from the input smoothing_matrix so edge-row
// renormalization is exact.

#define NFRAMES 16
#define NPATCH  196
#define EMBED   768
#define NBATCH  8
#define NTOKENS (NFRAMES * NPATCH + 1)   // 3137
#define E4      (EMBED / 4)              // 192 float4 per embed row
#define FSTRIDE (NPATCH * E4)            // float4 stride between frames

#define COL_TOTAL  (NBATCH * NPATCH * E4)      // 301,056 columns
#define HALF_TOTAL (2 * COL_TOTAL)             // 602,112 half-column threads
#define CLS_TOTAL  (NBATCH * E4)               // 1,536 cls-copy threads

template <int H>
__device__ __forceinline__ void do_half(const float4* __restrict__ x,
                                        float4* __restrict__ out,
                                        size_t base,
                                        const float* sWl, const float* sWc,
                                        const float* sWr) {
    constexpr int T0 = H * 8;            // first output frame
    constexpr int F0 = (H == 0) ? 0 : 7; // first loaded frame
    float4 v[9];
#pragma unroll
    for (int i = 0; i < 9; ++i)
        v[i] = x[base + (size_t)(F0 + i) * FSTRIDE];

#pragma unroll
    for (int i = 0; i < 8; ++i) {
        constexpr int unused = 0; (void)unused;
        int t = T0 + i;
        int c = t - F0;                  // compile-time after unroll
        float wc = sWc[t];
        float4 cv = v[c];
        float4 a;
        a.x = wc * cv.x; a.y = wc * cv.y; a.z = wc * cv.z; a.w = wc * cv.w;
        if (t > 0) {
            float wl = sWl[t];
            float4 l = v[c - 1];
            a.x += wl * l.x; a.y += wl * l.y; a.z += wl * l.z; a.w += wl * l.w;
        }
        if (t < NFRAMES - 1) {
            float wr = sWr[t];
            float4 r = v[c + 1];
            a.x += wr * r.x; a.y += wr * r.y; a.z += wr * r.z; a.w += wr * r.w;
        }
        out[base + (size_t)t * FSTRIDE] = a;
    }
}

__global__ void __launch_bounds__(256)
patch_blender_half_kernel(const float4* __restrict__ x,
                          const float* __restrict__ M,
                          float4* __restrict__ out) {
    __shared__ float sWl[NFRAMES], sWc[NFRAMES], sWr[NFRAMES];
    if (threadIdx.x < NFRAMES) {
        int t = threadIdx.x;
        sWl[t] = (t > 0)           ? M[t * NFRAMES + t - 1] : 0.0f;
        sWc[t] =                     M[t * NFRAMES + t];
        sWr[t] = (t < NFRAMES - 1) ? M[t * NFRAMES + t + 1] : 0.0f;
    }
    __syncthreads();

    int idx = blockIdx.x * blockDim.x + threadIdx.x;

    if (idx < HALF_TOTAL) {
        int e4    = idx % E4;
        int rest  = idx / E4;
        int p     = rest % NPATCH;
        int rest2 = rest / NPATCH;
        int b     = rest2 % NBATCH;
        int h     = rest2 / NBATCH;      // 0 = frames 0-7, 1 = frames 8-15

        // float4 index of frame 0's element in this column
        const size_t base = (size_t)b * NTOKENS * E4 + (size_t)(1 + p) * E4 + e4;

        if (h == 0) do_half<0>(x, out, base, sWl, sWc, sWr);
        else        do_half<1>(x, out, base, sWl, sWc, sWr);
    } else if (idx < HALF_TOTAL + CLS_TOTAL) {
        int j  = idx - HALF_TOTAL;
        int e4 = j % E4;
        int b  = j / E4;
        size_t o = (size_t)b * NTOKENS * E4 + e4;
        out[o] = x[o];                   // cls token passthrough
    }
}

extern "C" void kernel_launch(void* const* d_in, const int* in_sizes, int n_in,
                              void* d_out, int out_size, void* d_ws, size_t ws_size,
                              hipStream_t stream) {
    const float4* x = (const float4*)d_in[0];
    const float*  M = (const float*)d_in[1];
    float4* out = (float4*)d_out;

    const int total = HALF_TOTAL + CLS_TOTAL;    // 603,648
    int threads = 256;
    int blocks = (total + threads - 1) / threads; // 2358 blocks
    patch_blender_half_kernel<<<blocks, threads, 0, stream>>>(x, M, out);
}

// Round 5
// 28.414 us; speedup vs baseline: 1.0353x; 1.0353x over previous
//
#include <hip/hip_runtime.h>

// PatchBlender, column-per-thread (round-2 structure, best so far) + NT stores:
// Each thread owns one (b, p, e4) column across all 16 frames: 16 float4 loads,
// 16 float4 stores -> every input element fetched exactly once. Output is pure
// streaming (never re-read), so stores are non-temporal to avoid churning the
// 32 MB L2 against the read stream. Loads stay regular to keep L3 residency.
// Uses ext_vector_type(4) since __builtin_nontemporal_store rejects
// HIP_vector_type. Weights come from the input smoothing_matrix.

#define NFRAMES 16
#define NPATCH  196
#define EMBED   768
#define NBATCH  8
#define NTOKENS (NFRAMES * NPATCH + 1)   // 3137
#define E4      (EMBED / 4)              // 192 float4 per embed row
#define FSTRIDE (NPATCH * E4)            // float4 stride between frames

#define COL_TOTAL (NBATCH * NPATCH * E4) // 301,056 column threads
#define CLS_TOTAL (NBATCH * E4)          // 1,536 cls-copy threads

typedef float v4f __attribute__((ext_vector_type(4)));

__global__ void __launch_bounds__(256)
patch_blender_col_nt_kernel(const v4f* __restrict__ x,
                            const float* __restrict__ M,
                            v4f* __restrict__ out) {
    __shared__ float sWl[NFRAMES], sWc[NFRAMES], sWr[NFRAMES];
    if (threadIdx.x < NFRAMES) {
        int t = threadIdx.x;
        sWl[t] = (t > 0)           ? M[t * NFRAMES + t - 1] : 0.0f;
        sWc[t] =                     M[t * NFRAMES + t];
        sWr[t] = (t < NFRAMES - 1) ? M[t * NFRAMES + t + 1] : 0.0f;
    }
    __syncthreads();

    int idx = blockIdx.x * blockDim.x + threadIdx.x;

    if (idx < COL_TOTAL) {
        int e4   = idx % E4;
        int rest = idx / E4;
        int p    = rest % NPATCH;
        int b    = rest / NPATCH;

        // float4 index of frame 0's element in this column
        const size_t base = (size_t)b * NTOKENS * E4 + (size_t)(1 + p) * E4 + e4;

        v4f v[NFRAMES];
#pragma unroll
        for (int f = 0; f < NFRAMES; ++f)
            v[f] = x[base + (size_t)f * FSTRIDE];

#pragma unroll
        for (int t = 0; t < NFRAMES; ++t) {
            v4f a = sWc[t] * v[t];
            if (t > 0)           a += sWl[t] * v[t - 1];
            if (t < NFRAMES - 1) a += sWr[t] * v[t + 1];
            __builtin_nontemporal_store(a, &out[base + (size_t)t * FSTRIDE]);
        }
    } else if (idx < COL_TOTAL + CLS_TOTAL) {
        int j  = idx - COL_TOTAL;
        int e4 = j % E4;
        int b  = j / E4;
        size_t o = (size_t)b * NTOKENS * E4 + e4;
        v4f c = x[o];                    // cls token passthrough
        __builtin_nontemporal_store(c, &out[o]);
    }
}

extern "C" void kernel_launch(void* const* d_in, const int* in_sizes, int n_in,
                              void* d_out, int out_size, void* d_ws, size_t ws_size,
                              hipStream_t stream) {
    const v4f* x = (const v4f*)d_in[0];
    const float* M = (const float*)d_in[1];
    v4f* out = (v4f*)d_out;

    const int total = COL_TOTAL + CLS_TOTAL;      // 302,592
    int threads = 256;
    int blocks = (total + threads - 1) / threads; // 1182 blocks
    patch_blender_col_nt_kernel<<<blocks, threads, 0, stream>>>(x, M, out);
}

// Round 6
// 28.007 us; speedup vs baseline: 1.0504x; 1.0145x over previous
//
#include <hip/hip_runtime.h>

// PatchBlender, LDS-tiled: block = 256 threads owns 64 (p,e4) columns x 16
// frames (all within one patch-row since 64 | E4). Each thread: 4 coalesced
// 1KB global loads -> LDS tile [16][64], sync, 4 outputs (3 LDS taps each),
// 4 coalesced 1KB stores. Zero halo: every input element loaded exactly once.
// vs round-2 column kernel: same traffic but 16x more threads (18.8K waves,
// full occupancy) -> tests the latency/occupancy theory cleanly.

#define NFRAMES 16
#define NPATCH  196
#define EMBED   768
#define NBATCH  8
#define NTOKENS (NFRAMES * NPATCH + 1)   // 3137
#define E4      (EMBED / 4)              // 192 float4 per embed row
#define FSTRIDE (NPATCH * E4)            // float4 stride between frames

#define NCOLS    (NBATCH * NPATCH * E4)  // 301,056 columns
#define CPB      64                      // columns per block
#define NPBLOCKS (NCOLS / CPB)           // 4704 patch blocks (exact)
#define CLS_TOTAL (NBATCH * E4)          // 1,536 cls float4s
#define NCBLOCKS ((CLS_TOTAL + 255) / 256) // 6 cls blocks

typedef float v4f __attribute__((ext_vector_type(4)));

__global__ void __launch_bounds__(256)
patch_blender_lds_kernel(const v4f* __restrict__ x,
                         const float* __restrict__ M,
                         v4f* __restrict__ out) {
    int blk = blockIdx.x;
    int tid = threadIdx.x;

    if (blk >= NPBLOCKS) {               // cls token passthrough
        int j = (blk - NPBLOCKS) * 256 + tid;
        if (j < CLS_TOTAL) {
            int e4 = j % E4;
            int b  = j / E4;
            size_t o = (size_t)b * NTOKENS * E4 + e4;
            out[o] = x[o];
        }
        return;
    }

    __shared__ float sWl[NFRAMES], sWc[NFRAMES], sWr[NFRAMES];
    __shared__ v4f tile[NFRAMES][CPB];

    if (tid < NFRAMES) {
        int t = tid;
        sWl[t] = (t > 0)           ? M[t * NFRAMES + t - 1] : 0.0f;
        sWc[t] =                     M[t * NFRAMES + t];
        sWr[t] = (t < NFRAMES - 1) ? M[t * NFRAMES + t + 1] : 0.0f;
    }

    // Block's 64 columns are contiguous and lie within one (b, p) row.
    int col0 = blk * CPB;
    int e4_0 = col0 % E4;
    int p    = (col0 / E4) % NPATCH;
    int b    = col0 / (E4 * NPATCH);

    int c  = tid & 63;                   // column within block (lane-contiguous)
    int tb = tid >> 6;                   // wave index 0..3

    // float4 index of frame 0's element for this thread's column
    const size_t base = (size_t)b * NTOKENS * E4 + (size_t)(1 + p) * E4 + e4_0 + c;

#pragma unroll
    for (int i = 0; i < 4; ++i) {
        int t = tb + 4 * i;
        tile[t][c] = x[base + (size_t)t * FSTRIDE];
    }
    __syncthreads();

#pragma unroll
    for (int i = 0; i < 4; ++i) {
        int t  = tb + 4 * i;
        int tl = (t == 0)           ? 0           : t - 1;  // sWl[0] == 0
        int tr = (t == NFRAMES - 1) ? NFRAMES - 1 : t + 1;  // sWr[15] == 0
        v4f a = sWc[t] * tile[t][c];
        a += sWl[t] * tile[tl][c];
        a += sWr[t] * tile[tr][c];
        out[base + (size_t)t * FSTRIDE] = a;
    }
}

extern "C" void kernel_launch(void* const* d_in, const int* in_sizes, int n_in,
                              void* d_out, int out_size, void* d_ws, size_t ws_size,
                              hipStream_t stream) {
    const v4f* x = (const v4f*)d_in[0];
    const float* M = (const float*)d_in[1];
    v4f* out = (v4f*)d_out;

    int blocks = NPBLOCKS + NCBLOCKS;    // 4710
    patch_blender_lds_kernel<<<blocks, 256, 0, stream>>>(x, M, out);
}